// Round 2
// baseline (393.817 us; speedup 1.0000x reference)
//
#include <hip/hip_runtime.h>
#include <math.h>

#define Nn 1536
#define Bb 2
#define Pp 1178880   // Nn*(Nn-1)/2
#define Hh 32
#define Ll 16

__device__ __forceinline__ int triu_off(int i) {
    // offset of first pair with row i in triu(k=1) row-major enumeration
    return i * (2 * Nn - 1 - i) / 2;
}

// ---------------- deg / dinv / diagadj ----------------
// one wave per (b,i) row
__global__ void deg_kernel(const float* __restrict__ A,
                           float* __restrict__ dinv, float* __restrict__ diagadj) {
    int w = threadIdx.x >> 6;
    int lane = threadIdx.x & 63;
    int bi = blockIdx.x * 4 + w;
    if (bi >= Bb * Nn) return;
    const float* Arow = A + (size_t)bi * Nn;
    float s = 0.f;
    for (int j = lane; j < Nn; j += 64) s += Arow[j];
#pragma unroll
    for (int o = 32; o > 0; o >>= 1) s += __shfl_down(s, o, 64);
    if (lane == 0) {
        int i = bi % Nn;
        float d = Arow[i];
        float fill = (d == 0.f) ? 1.f : d;
        float da = fill - d;              // A_hat diag minus A diag
        float deg = s + da;               // rowsum - d + fill
        dinv[bi] = (deg > 0.f) ? (1.f / sqrtf(deg)) : 0.f;
        diagadj[bi] = da;
    }
}

// ---------------- xs = dinv * (x @ W) ----------------
// x: [B,N,Cin] (xstride_b elements per batch; 0 => broadcast emb), W: [Cin,32]
__global__ void xs_kernel(const float* __restrict__ x, int xstride_b, int Cin,
                          const float* __restrict__ W,
                          const float* __restrict__ dinv, float* __restrict__ xs) {
    int t = blockIdx.x * 256 + threadIdx.x;
    if (t >= Bb * Nn * Hh) return;
    int c = t & (Hh - 1);
    int bi = t >> 5;
    int b = bi / Nn;
    int i = bi - b * Nn;
    const float* xr = x + (size_t)b * xstride_b + (size_t)i * Cin;
    float acc = 0.f;
    for (int m = 0; m < Cin; ++m) acc = fmaf(xr[m], W[m * Hh + c], acc);
    xs[(size_t)bi * Hh + c] = dinv[bi] * acc;
}

// ---------------- GCN propagation: out = relu(dinv_i * (A_hat @ xs) + bias) [+ res] ----------------
// one block per (b,i) row
__global__ void prop_kernel(const float* __restrict__ A, const float* __restrict__ xs,
                            const float* __restrict__ dinv, const float* __restrict__ diagadj,
                            const float* __restrict__ bias, const float* __restrict__ res,
                            float* __restrict__ out, int has_res) {
    __shared__ float sA[Nn];                 // 6 KB
    __shared__ float sred[32 * 32];          // 4 KB
    int bi = blockIdx.x;
    int b = bi / Nn;
    int i = bi - b * Nn;
    const float* Arow = A + (size_t)bi * Nn;
    for (int t = threadIdx.x; t < Nn; t += 256) sA[t] = Arow[t];
    __syncthreads();

    int c4 = (threadIdx.x & 7) << 2;         // column base (0..28)
    int grp = threadIdx.x >> 3;              // 0..31, each handles 48 j's
    const float* xsb = xs + (size_t)b * Nn * Hh;
    float a0 = 0.f, a1 = 0.f, a2 = 0.f, a3 = 0.f;
    int j0 = grp * 48;
#pragma unroll 4
    for (int jj = 0; jj < 48; ++jj) {
        int j = j0 + jj;
        float a = sA[j];
        const float4 x4 = *reinterpret_cast<const float4*>(xsb + (size_t)j * Hh + c4);
        a0 = fmaf(a, x4.x, a0);
        a1 = fmaf(a, x4.y, a1);
        a2 = fmaf(a, x4.z, a2);
        a3 = fmaf(a, x4.w, a3);
    }
    sred[grp * 32 + c4 + 0] = a0;
    sred[grp * 32 + c4 + 1] = a1;
    sred[grp * 32 + c4 + 2] = a2;
    sred[grp * 32 + c4 + 3] = a3;
    __syncthreads();
    for (int s = 16; s > 0; s >>= 1) {
        if (grp < s) {
#pragma unroll
            for (int k = 0; k < 4; ++k)
                sred[grp * 32 + c4 + k] += sred[(grp + s) * 32 + c4 + k];
        }
        __syncthreads();
    }
    if (grp == 0) {
        float di = dinv[bi], da = diagadj[bi];
#pragma unroll
        for (int k = 0; k < 4; ++k) {
            int c = c4 + k;
            float v = sred[c] + da * xsb[(size_t)i * Hh + c];  // diag correction
            v = di * v + bias[c];
            v = fmaxf(v, 0.f);
            if (has_res) v += res[(size_t)bi * Hh + c];
            out[(size_t)bi * Hh + c] = v;
        }
    }
}

// ---------------- mu / logvar heads + diag zeros ----------------
__global__ void mulv_kernel(const float* __restrict__ h3,
                            const float* __restrict__ Wmu, const float* __restrict__ bmu,
                            const float* __restrict__ Wlv, const float* __restrict__ blv,
                            float* __restrict__ mu, float* __restrict__ lv,
                            float* __restrict__ adj) {
    int t = blockIdx.x * 256 + threadIdx.x;
    if (t >= Bb * Nn * Ll) return;
    int l = t & (Ll - 1);
    int bi = t >> 4;
    const float* h = h3 + (size_t)bi * Hh;
    float am = bmu[l], av = blv[l];
#pragma unroll
    for (int c = 0; c < Hh; ++c) {
        float hv = h[c];
        am = fmaf(hv, Wmu[c * Ll + l], am);
        av = fmaf(hv, Wlv[c * Ll + l], av);
    }
    mu[(size_t)bi * Ll + l] = am;
    lv[(size_t)bi * Ll + l] = av;
    if (l == 0) {
        int b = bi / Nn, i = bi - b * Nn;
        adj[(size_t)b * Nn * Nn + (size_t)i * Nn + i] = 0.f;  // zero diagonal
    }
}

// ---------------- edge MLP over all (i<j) pairs, both batches ----------------
__global__ __launch_bounds__(256) void edge_kernel(
    const float* __restrict__ z,
    const float* __restrict__ E1, const float* __restrict__ e1,
    const float* __restrict__ E2, const float* __restrict__ e2,
    const float* __restrict__ E3, const float* __restrict__ e3,
    float* __restrict__ adj) {
    __shared__ __align__(16) float sE1[32 * 64];
    __shared__ __align__(16) float sE2[64 * 32];
    __shared__ __align__(16) float sE3[32];
    __shared__ __align__(16) float se1[64];
    __shared__ __align__(16) float se2[32];
    __shared__ float se3;
    int t = threadIdx.x;
    for (int k = t; k < 2048; k += 256) { sE1[k] = E1[k]; sE2[k] = E2[k]; }
    if (t < 64) se1[t] = e1[t];
    if (t < 32) { se2[t] = e2[t]; sE3[t] = E3[t]; }
    if (t == 0) se3 = e3[0];
    __syncthreads();

    int gid = blockIdx.x * 256 + t;
    if (gid >= Bb * Pp) return;
    int b = gid / Pp;
    int p = gid - b * Pp;

    // invert triu row-major pair index -> (i, j)
    double disc = (double)(2 * Nn - 1) * (2 * Nn - 1) - 8.0 * (double)p;
    int i = (int)(((2.0 * Nn - 1) - sqrt(disc)) * 0.5);
    if (i < 0) i = 0;
    if (i > Nn - 2) i = Nn - 2;
    while (i < Nn - 2 && triu_off(i + 1) <= p) ++i;
    while (i > 0 && triu_off(i) > p) --i;
    int j = i + 1 + (p - triu_off(i));

    const float* zi = z + ((size_t)b * Nn + i) * Ll;
    const float* zj = z + ((size_t)b * Nn + j) * Ll;
    float f[32];
#pragma unroll
    for (int q = 0; q < 4; ++q) {
        float4 v = reinterpret_cast<const float4*>(zi)[q];
        f[q * 4 + 0] = v.x; f[q * 4 + 1] = v.y; f[q * 4 + 2] = v.z; f[q * 4 + 3] = v.w;
    }
#pragma unroll
    for (int q = 0; q < 4; ++q) {
        float4 v = reinterpret_cast<const float4*>(zj)[q];
        f[16 + q * 4 + 0] = v.x; f[16 + q * 4 + 1] = v.y;
        f[16 + q * 4 + 2] = v.z; f[16 + q * 4 + 3] = v.w;
    }

    float h1v[64];
#pragma unroll
    for (int k4 = 0; k4 < 16; ++k4) {
        float ax = se1[k4 * 4 + 0], ay = se1[k4 * 4 + 1];
        float az = se1[k4 * 4 + 2], aw = se1[k4 * 4 + 3];
#pragma unroll
        for (int m = 0; m < 32; ++m) {
            const float4 w = *reinterpret_cast<const float4*>(&sE1[m * 64 + k4 * 4]);
            float fm = f[m];
            ax = fmaf(fm, w.x, ax);
            ay = fmaf(fm, w.y, ay);
            az = fmaf(fm, w.z, az);
            aw = fmaf(fm, w.w, aw);
        }
        h1v[k4 * 4 + 0] = fmaxf(ax, 0.f);
        h1v[k4 * 4 + 1] = fmaxf(ay, 0.f);
        h1v[k4 * 4 + 2] = fmaxf(az, 0.f);
        h1v[k4 * 4 + 3] = fmaxf(aw, 0.f);
    }

    float h2v[32];
#pragma unroll
    for (int c4 = 0; c4 < 8; ++c4) {
        float ax = se2[c4 * 4 + 0], ay = se2[c4 * 4 + 1];
        float az = se2[c4 * 4 + 2], aw = se2[c4 * 4 + 3];
#pragma unroll
        for (int k = 0; k < 64; ++k) {
            const float4 w = *reinterpret_cast<const float4*>(&sE2[k * 32 + c4 * 4]);
            float hk = h1v[k];
            ax = fmaf(hk, w.x, ax);
            ay = fmaf(hk, w.y, ay);
            az = fmaf(hk, w.z, az);
            aw = fmaf(hk, w.w, aw);
        }
        h2v[c4 * 4 + 0] = fmaxf(ax, 0.f);
        h2v[c4 * 4 + 1] = fmaxf(ay, 0.f);
        h2v[c4 * 4 + 2] = fmaxf(az, 0.f);
        h2v[c4 * 4 + 3] = fmaxf(aw, 0.f);
    }

    float acc = se3;
#pragma unroll
    for (int c = 0; c < 32; ++c) acc = fmaf(h2v[c], sE3[c], acc);
    float wv = 1.f / (1.f + __expf(-acc));

    size_t base = (size_t)b * Nn * Nn;
    adj[base + (size_t)i * Nn + j] = wv;
    adj[base + (size_t)j * Nn + i] = wv;
}

extern "C" void kernel_launch(void* const* d_in, const int* in_sizes, int n_in,
                              void* d_out, int out_size, void* d_ws, size_t ws_size,
                              hipStream_t stream) {
    const float* A   = (const float*)d_in[0];
    const float* emb = (const float*)d_in[1];
    const float* W1  = (const float*)d_in[2];  const float* b1  = (const float*)d_in[3];
    const float* W2  = (const float*)d_in[4];  const float* b2  = (const float*)d_in[5];
    const float* W3  = (const float*)d_in[6];  const float* b3  = (const float*)d_in[7];
    const float* Wmu = (const float*)d_in[8];  const float* bmu = (const float*)d_in[9];
    const float* Wlv = (const float*)d_in[10]; const float* blv = (const float*)d_in[11];
    const float* E1  = (const float*)d_in[12]; const float* e1  = (const float*)d_in[13];
    const float* E2  = (const float*)d_in[14]; const float* e2  = (const float*)d_in[15];
    const float* E3  = (const float*)d_in[16]; const float* e3  = (const float*)d_in[17];

    float* out = (float*)d_out;
    float* ws  = (float*)d_ws;
    // ws layout (floats): dinv[3072] | diagadj[3072] | xs[98304] | hA[98304] | hB[98304]
    float* dinv = ws;
    float* dadj = ws + 3072;
    float* xs   = ws + 6144;
    float* hA   = ws + 104448;
    float* hB   = ws + 202752;

    float* mu_out = out + (size_t)Bb * Nn * Nn;
    float* lv_out = mu_out + (size_t)Bb * Nn * Ll;

    deg_kernel<<<(Bb * Nn + 3) / 4, 256, 0, stream>>>(A, dinv, dadj);

    // layer 1: x = emb (broadcast), Cin = 8
    xs_kernel<<<(Bb * Nn * Hh + 255) / 256, 256, 0, stream>>>(emb, 0, 8, W1, dinv, xs);
    prop_kernel<<<Bb * Nn, 256, 0, stream>>>(A, xs, dinv, dadj, b1, nullptr, hA, 0);
    // layer 2
    xs_kernel<<<(Bb * Nn * Hh + 255) / 256, 256, 0, stream>>>(hA, Nn * Hh, Hh, W2, dinv, xs);
    prop_kernel<<<Bb * Nn, 256, 0, stream>>>(A, xs, dinv, dadj, b2, hA, hB, 1);
    // layer 3
    xs_kernel<<<(Bb * Nn * Hh + 255) / 256, 256, 0, stream>>>(hB, Nn * Hh, Hh, W3, dinv, xs);
    prop_kernel<<<Bb * Nn, 256, 0, stream>>>(A, xs, dinv, dadj, b3, hB, hA, 1);

    mulv_kernel<<<(Bb * Nn * Ll + 255) / 256, 256, 0, stream>>>(hA, Wmu, bmu, Wlv, blv,
                                                                mu_out, lv_out, out);

    edge_kernel<<<(Bb * Pp + 255) / 256, 256, 0, stream>>>(mu_out, E1, e1, E2, e2, E3, e3, out);
}

// Round 3
// 215.432 us; speedup vs baseline: 1.8280x; 1.8280x over previous
//
#include <hip/hip_runtime.h>
#include <math.h>

#define Nn 1536
#define Bb 2
#define Pp 1178880   // Nn*(Nn-1)/2
#define Hh 32
#define Ll 16
#define TPW 8        // tiles per wave in edge kernel

typedef short bf16x8 __attribute__((ext_vector_type(8)));
typedef float f32x4 __attribute__((ext_vector_type(4)));

__device__ __forceinline__ int triu_off(int i) {
    return i * (2 * Nn - 1 - i) / 2;
}

__device__ __forceinline__ short f2bf(float x) {
    union { float f; unsigned u; } a; a.f = x;
    unsigned r = a.u + 0x7FFF + ((a.u >> 16) & 1);  // RNE
    return (short)(r >> 16);
}

// ---------------- deg / dinv / diagadj ----------------
__global__ void deg_kernel(const float* __restrict__ A,
                           float* __restrict__ dinv, float* __restrict__ diagadj) {
    int w = threadIdx.x >> 6;
    int lane = threadIdx.x & 63;
    int bi = blockIdx.x * 4 + w;
    if (bi >= Bb * Nn) return;
    const float* Arow = A + (size_t)bi * Nn;
    float s = 0.f;
    for (int j = lane; j < Nn; j += 64) s += Arow[j];
#pragma unroll
    for (int o = 32; o > 0; o >>= 1) s += __shfl_down(s, o, 64);
    if (lane == 0) {
        int i = bi % Nn;
        float d = Arow[i];
        float fill = (d == 0.f) ? 1.f : d;
        float da = fill - d;
        float deg = s + da;
        dinv[bi] = (deg > 0.f) ? (1.f / sqrtf(deg)) : 0.f;
        diagadj[bi] = da;
    }
}

// ---------------- xs = dinv * (x @ W) ----------------
__global__ void xs_kernel(const float* __restrict__ x, int xstride_b, int Cin,
                          const float* __restrict__ W,
                          const float* __restrict__ dinv, float* __restrict__ xs) {
    int t = blockIdx.x * 256 + threadIdx.x;
    if (t >= Bb * Nn * Hh) return;
    int c = t & (Hh - 1);
    int bi = t >> 5;
    int b = bi / Nn;
    int i = bi - b * Nn;
    const float* xr = x + (size_t)b * xstride_b + (size_t)i * Cin;
    float acc = 0.f;
    for (int m = 0; m < Cin; ++m) acc = fmaf(xr[m], W[m * Hh + c], acc);
    xs[(size_t)bi * Hh + c] = dinv[bi] * acc;
}

// ---------------- GCN propagation ----------------
__global__ void prop_kernel(const float* __restrict__ A, const float* __restrict__ xs,
                            const float* __restrict__ dinv, const float* __restrict__ diagadj,
                            const float* __restrict__ bias, const float* __restrict__ res,
                            float* __restrict__ out, int has_res) {
    __shared__ float sA[Nn];
    __shared__ float sred[32 * 32];
    int bi = blockIdx.x;
    int b = bi / Nn;
    int i = bi - b * Nn;
    const float* Arow = A + (size_t)bi * Nn;
    for (int t = threadIdx.x; t < Nn; t += 256) sA[t] = Arow[t];
    __syncthreads();

    int c4 = (threadIdx.x & 7) << 2;
    int grp = threadIdx.x >> 3;
    const float* xsb = xs + (size_t)b * Nn * Hh;
    float a0 = 0.f, a1 = 0.f, a2 = 0.f, a3 = 0.f;
    int j0 = grp * 48;
#pragma unroll 4
    for (int jj = 0; jj < 48; ++jj) {
        int j = j0 + jj;
        float a = sA[j];
        const float4 x4 = *reinterpret_cast<const float4*>(xsb + (size_t)j * Hh + c4);
        a0 = fmaf(a, x4.x, a0);
        a1 = fmaf(a, x4.y, a1);
        a2 = fmaf(a, x4.z, a2);
        a3 = fmaf(a, x4.w, a3);
    }
    sred[grp * 32 + c4 + 0] = a0;
    sred[grp * 32 + c4 + 1] = a1;
    sred[grp * 32 + c4 + 2] = a2;
    sred[grp * 32 + c4 + 3] = a3;
    __syncthreads();
    for (int s = 16; s > 0; s >>= 1) {
        if (grp < s) {
#pragma unroll
            for (int k = 0; k < 4; ++k)
                sred[grp * 32 + c4 + k] += sred[(grp + s) * 32 + c4 + k];
        }
        __syncthreads();
    }
    if (grp == 0) {
        float di = dinv[bi], da = diagadj[bi];
#pragma unroll
        for (int k = 0; k < 4; ++k) {
            int c = c4 + k;
            float v = sred[c] + da * xsb[(size_t)i * Hh + c];
            v = di * v + bias[c];
            v = fmaxf(v, 0.f);
            if (has_res) v += res[(size_t)bi * Hh + c];
            out[(size_t)bi * Hh + c] = v;
        }
    }
}

// ---------------- mu / logvar heads + diag zeros ----------------
__global__ void mulv_kernel(const float* __restrict__ h3,
                            const float* __restrict__ Wmu, const float* __restrict__ bmu,
                            const float* __restrict__ Wlv, const float* __restrict__ blv,
                            float* __restrict__ mu, float* __restrict__ lv,
                            float* __restrict__ adj) {
    int t = blockIdx.x * 256 + threadIdx.x;
    if (t >= Bb * Nn * Ll) return;
    int l = t & (Ll - 1);
    int bi = t >> 4;
    const float* h = h3 + (size_t)bi * Hh;
    float am = bmu[l], av = blv[l];
#pragma unroll
    for (int c = 0; c < Hh; ++c) {
        float hv = h[c];
        am = fmaf(hv, Wmu[c * Ll + l], am);
        av = fmaf(hv, Wlv[c * Ll + l], av);
    }
    mu[(size_t)bi * Ll + l] = am;
    lv[(size_t)bi * Ll + l] = av;
    if (l == 0) {
        int b = bi / Nn, i = bi - b * Nn;
        adj[(size_t)b * Nn * Nn + (size_t)i * Nn + i] = 0.f;
    }
}

// ---------------- U/V precompute: U = z@E1_top + e1, V = z@E1_bot ----------------
__global__ void uv_kernel(const float* __restrict__ z, const float* __restrict__ E1,
                          const float* __restrict__ e1,
                          float* __restrict__ U, float* __restrict__ V) {
    int t = blockIdx.x * 256 + threadIdx.x;
    if (t >= Bb * Nn * 64) return;
    int c = t & 63;
    int bi = t >> 6;
    const float* zr = z + (size_t)bi * Ll;
    float au = e1[c], av = 0.f;
#pragma unroll
    for (int m = 0; m < Ll; ++m) {
        float zv = zr[m];
        au = fmaf(zv, E1[m * 64 + c], au);
        av = fmaf(zv, E1[(16 + m) * 64 + c], av);
    }
    U[t] = au;
    V[t] = av;
}

// ---------------- edge MLP: MFMA layer2, VALU layer3 ----------------
__global__ __launch_bounds__(256) void edge_mfma_kernel(
    const float* __restrict__ U, const float* __restrict__ V,
    const float* __restrict__ E2, const float* __restrict__ e2,
    const float* __restrict__ E3, const float* __restrict__ e3,
    float* __restrict__ adj) {
    int t = threadIdx.x;
    int lane = t & 63;
    int wv = t >> 6;
    int g = lane >> 4;        // 0..3 (k-group)
    int r16 = lane & 15;      // pair row (A) / out channel (C)

    // B-fragments of E2 (loop-invariant): lane holds E2[32s+8g+j][16nt+r16]
    bf16x8 bfr[2][2];
#pragma unroll
    for (int s = 0; s < 2; ++s)
#pragma unroll
        for (int nt = 0; nt < 2; ++nt)
#pragma unroll
            for (int jj = 0; jj < 8; ++jj)
                bfr[s][nt][jj] = f2bf(E2[(32 * s + 8 * g + jj) * Hh + 16 * nt + r16]);

    float e2c0 = e2[r16], e2c1 = e2[16 + r16];
    float E3c0 = E3[r16], E3c1 = E3[16 + r16];
    float e3s = e3[0];

    long tile0 = ((long)blockIdx.x * 4 + wv) * TPW;
#pragma unroll 1
    for (int it = 0; it < TPW; ++it) {
        long tile = tile0 + it;
        int b = (int)(tile / (Pp / 16));
        int pt = (int)(tile - (long)b * (Pp / 16));
        int p = pt * 16 + r16;

        // invert triu pair index -> (i, j)
        double disc = (double)(2 * Nn - 1) * (2 * Nn - 1) - 8.0 * (double)p;
        int i = (int)(((2.0 * Nn - 1) - sqrt(disc)) * 0.5);
        if (i < 0) i = 0;
        if (i > Nn - 2) i = Nn - 2;
        while (i < Nn - 2 && triu_off(i + 1) <= p) ++i;
        while (i > 0 && triu_off(i) > p) --i;
        int j = i + 1 + (p - triu_off(i));

        const float* Up = U + ((size_t)b * Nn + i) * 64 + 8 * g;
        const float* Vp = V + ((size_t)b * Nn + j) * 64 + 8 * g;
        float4 u0 = *(const float4*)(Up);
        float4 u1 = *(const float4*)(Up + 4);
        float4 u2 = *(const float4*)(Up + 32);
        float4 u3 = *(const float4*)(Up + 36);
        float4 v0 = *(const float4*)(Vp);
        float4 v1 = *(const float4*)(Vp + 4);
        float4 v2 = *(const float4*)(Vp + 32);
        float4 v3 = *(const float4*)(Vp + 36);

        // A-fragments: h1 = relu(U+V) in bf16; af0 covers k=8g..8g+7, af1 k=32+8g..+7
        bf16x8 af0, af1;
        af0[0] = f2bf(fmaxf(u0.x + v0.x, 0.f));
        af0[1] = f2bf(fmaxf(u0.y + v0.y, 0.f));
        af0[2] = f2bf(fmaxf(u0.z + v0.z, 0.f));
        af0[3] = f2bf(fmaxf(u0.w + v0.w, 0.f));
        af0[4] = f2bf(fmaxf(u1.x + v1.x, 0.f));
        af0[5] = f2bf(fmaxf(u1.y + v1.y, 0.f));
        af0[6] = f2bf(fmaxf(u1.z + v1.z, 0.f));
        af0[7] = f2bf(fmaxf(u1.w + v1.w, 0.f));
        af1[0] = f2bf(fmaxf(u2.x + v2.x, 0.f));
        af1[1] = f2bf(fmaxf(u2.y + v2.y, 0.f));
        af1[2] = f2bf(fmaxf(u2.z + v2.z, 0.f));
        af1[3] = f2bf(fmaxf(u2.w + v2.w, 0.f));
        af1[4] = f2bf(fmaxf(u3.x + v3.x, 0.f));
        af1[5] = f2bf(fmaxf(u3.y + v3.y, 0.f));
        af1[6] = f2bf(fmaxf(u3.z + v3.z, 0.f));
        af1[7] = f2bf(fmaxf(u3.w + v3.w, 0.f));

        // layer 2: h2[16 pairs][32] = h1 @ E2
        f32x4 acc0 = {0.f, 0.f, 0.f, 0.f};
        f32x4 acc1 = {0.f, 0.f, 0.f, 0.f};
        acc0 = __builtin_amdgcn_mfma_f32_16x16x32_bf16(af0, bfr[0][0], acc0, 0, 0, 0);
        acc0 = __builtin_amdgcn_mfma_f32_16x16x32_bf16(af1, bfr[1][0], acc0, 0, 0, 0);
        acc1 = __builtin_amdgcn_mfma_f32_16x16x32_bf16(af0, bfr[0][1], acc1, 0, 0, 0);
        acc1 = __builtin_amdgcn_mfma_f32_16x16x32_bf16(af1, bfr[1][1], acc1, 0, 0, 0);

        // layer 3: logit[row] = sum_c relu(h2 + e2)[row][c] * E3[c]
        float part[4];
#pragma unroll
        for (int rg = 0; rg < 4; ++rg) {
            float h20 = fmaxf(acc0[rg] + e2c0, 0.f);
            float h21 = fmaxf(acc1[rg] + e2c1, 0.f);
            part[rg] = fmaf(h20, E3c0, h21 * E3c1);
        }
#pragma unroll
        for (int m = 1; m < 16; m <<= 1)
#pragma unroll
            for (int rg = 0; rg < 4; ++rg)
                part[rg] += __shfl_xor(part[rg], m, 64);

        // lane whose own pair-row r16 lies in this lane-group's C rows writes it
        if ((r16 >> 2) == g) {
            float logit = part[r16 & 3] + e3s;
            float w = 1.f / (1.f + __expf(-logit));
            size_t base = (size_t)b * Nn * Nn;
            adj[base + (size_t)i * Nn + j] = w;
            adj[base + (size_t)j * Nn + i] = w;
        }
    }
}

extern "C" void kernel_launch(void* const* d_in, const int* in_sizes, int n_in,
                              void* d_out, int out_size, void* d_ws, size_t ws_size,
                              hipStream_t stream) {
    const float* A   = (const float*)d_in[0];
    const float* emb = (const float*)d_in[1];
    const float* W1  = (const float*)d_in[2];  const float* b1  = (const float*)d_in[3];
    const float* W2  = (const float*)d_in[4];  const float* b2  = (const float*)d_in[5];
    const float* W3  = (const float*)d_in[6];  const float* b3  = (const float*)d_in[7];
    const float* Wmu = (const float*)d_in[8];  const float* bmu = (const float*)d_in[9];
    const float* Wlv = (const float*)d_in[10]; const float* blv = (const float*)d_in[11];
    const float* E1  = (const float*)d_in[12]; const float* e1  = (const float*)d_in[13];
    const float* E2  = (const float*)d_in[14]; const float* e2  = (const float*)d_in[15];
    const float* E3  = (const float*)d_in[16]; const float* e3  = (const float*)d_in[17];

    float* out = (float*)d_out;
    float* ws  = (float*)d_ws;
    // ws layout (floats): dinv[3072] dadj[3072] xs[98304] hA[98304] hB[98304] U[196608] V[196608]
    float* dinv = ws;
    float* dadj = ws + 3072;
    float* xs   = ws + 6144;
    float* hA   = ws + 104448;
    float* hB   = ws + 202752;
    float* Ubuf = ws + 301056;
    float* Vbuf = ws + 497664;

    float* mu_out = out + (size_t)Bb * Nn * Nn;
    float* lv_out = mu_out + (size_t)Bb * Nn * Ll;

    deg_kernel<<<(Bb * Nn + 3) / 4, 256, 0, stream>>>(A, dinv, dadj);

    xs_kernel<<<(Bb * Nn * Hh + 255) / 256, 256, 0, stream>>>(emb, 0, 8, W1, dinv, xs);
    prop_kernel<<<Bb * Nn, 256, 0, stream>>>(A, xs, dinv, dadj, b1, nullptr, hA, 0);
    xs_kernel<<<(Bb * Nn * Hh + 255) / 256, 256, 0, stream>>>(hA, Nn * Hh, Hh, W2, dinv, xs);
    prop_kernel<<<Bb * Nn, 256, 0, stream>>>(A, xs, dinv, dadj, b2, hA, hB, 1);
    xs_kernel<<<(Bb * Nn * Hh + 255) / 256, 256, 0, stream>>>(hB, Nn * Hh, Hh, W3, dinv, xs);
    prop_kernel<<<Bb * Nn, 256, 0, stream>>>(A, xs, dinv, dadj, b3, hB, hA, 1);

    mulv_kernel<<<(Bb * Nn * Ll + 255) / 256, 256, 0, stream>>>(hA, Wmu, bmu, Wlv, blv,
                                                                mu_out, lv_out, out);

    uv_kernel<<<(Bb * Nn * 64 + 255) / 256, 256, 0, stream>>>(mu_out, E1, e1, Ubuf, Vbuf);

    // 147360 tiles total / (4 waves * TPW tiles) = 4605 blocks
    edge_mfma_kernel<<<(Bb * (Pp / 16)) / (4 * TPW), 256, 0, stream>>>(
        Ubuf, Vbuf, E2, e2, E3, e3, out);
}

// Round 4
// 111.149 us; speedup vs baseline: 3.5431x; 1.9382x over previous
//
#include <hip/hip_runtime.h>
#include <hip/hip_bf16.h>
#include <math.h>

#define Nn 1536
#define Bb 2
#define Hh 32
#define Ll 16
#define Nb 96          // Nn/16
#define TREG 4656      // Nb*(Nb+1)/2 regions per batch
#define KSTEPS 48      // 1536/32

typedef short bf16x8 __attribute__((ext_vector_type(8)));
typedef float f32x4 __attribute__((ext_vector_type(4)));
typedef short short4v __attribute__((ext_vector_type(4)));

__device__ __forceinline__ short f2bf(float x) {
    __hip_bfloat16 h = __float2bfloat16(x);
    return *reinterpret_cast<short*>(&h);
}

// ---------------- prep: rowsum -> dinv, and A -> bf16 with self-loop fill on diag ----------------
// one wave per (b,i) row
__global__ void prep_kernel(const float* __restrict__ A,
                            __hip_bfloat16* __restrict__ Abf,
                            float* __restrict__ dinv) {
    int w = threadIdx.x >> 6;
    int lane = threadIdx.x & 63;
    int bi = blockIdx.x * 4 + w;
    if (bi >= Bb * Nn) return;
    int i = (bi >= Nn) ? bi - Nn : bi;
    const float* Arow = A + (size_t)bi * Nn;
    short* Brow = (short*)Abf + (size_t)bi * Nn;
    float s = 0.f;
#pragma unroll
    for (int it = 0; it < 6; ++it) {
        int j = it * 256 + lane * 4;
        float4 a4 = *reinterpret_cast<const float4*>(Arow + j);
        s += a4.x + a4.y + a4.z + a4.w;
        float e0 = (j + 0 == i) ? ((a4.x == 0.f) ? 1.f : a4.x) : a4.x;
        float e1 = (j + 1 == i) ? ((a4.y == 0.f) ? 1.f : a4.y) : a4.y;
        float e2v = (j + 2 == i) ? ((a4.z == 0.f) ? 1.f : a4.z) : a4.z;
        float e3v = (j + 3 == i) ? ((a4.w == 0.f) ? 1.f : a4.w) : a4.w;
        short4v sv = { f2bf(e0), f2bf(e1), f2bf(e2v), f2bf(e3v) };
        *reinterpret_cast<short4v*>(Brow + j) = sv;
    }
#pragma unroll
    for (int o = 32; o > 0; o >>= 1) s += __shfl_down(s, o, 64);
    if (lane == 0) {
        float d = Arow[i];
        float fill = (d == 0.f) ? 1.f : d;
        float deg = s - d + fill;
        dinv[bi] = (deg > 0.f) ? (1.f / sqrtf(deg)) : 0.f;
    }
}

// ---------------- xsT[b][c][i] = bf16( dinv_i * (x @ W)[i][c] ) ----------------
// grid (6, Bb*32), block 256; x stride 0 => broadcast emb
__global__ void xsT_kernel(const float* __restrict__ x, int xstride_b, int Cin,
                           const float* __restrict__ W,
                           const float* __restrict__ dinv,
                           __hip_bfloat16* __restrict__ xsT) {
    int bc = blockIdx.y;                 // b*32 + c
    int b = bc >> 5, c = bc & 31;
    int i = blockIdx.x * 256 + threadIdx.x;
    const float* xr = x + (size_t)b * xstride_b + (size_t)i * Cin;
    float acc = 0.f;
    for (int m = 0; m < Cin; ++m) acc = fmaf(xr[m], W[m * Hh + c], acc);
    acc *= dinv[b * Nn + i];
    ((short*)xsT)[(size_t)bc * Nn + i] = f2bf(acc);
}

// ---------------- GCN propagation via MFMA: out = relu(dinv_i * (Abf @ xs) + bias) [+ res] ----------------
// block = 256 thr = 4 waves; block -> one 16-row M-tile; wave w -> 12 k-steps
__global__ __launch_bounds__(256) void prop_kernel(
    const __hip_bfloat16* __restrict__ Abf, const __hip_bfloat16* __restrict__ xsT,
    const float* __restrict__ dinv, const float* __restrict__ bias,
    const float* __restrict__ res, float* __restrict__ out, int has_res) {
    __shared__ float sRed[4][64][8];
    int t = threadIdx.x, lane = t & 63, w = t >> 6;
    int x = lane & 15, g = lane >> 4;
    int mt = blockIdx.x;                 // 0..191
    int b = mt / Nb, it = mt - b * Nb;
    int i0 = it * 16;

    const short* Arow = (const short*)Abf + ((size_t)b * Nn + i0 + x) * Nn + 8 * g;
    const short* X0 = (const short*)xsT + ((size_t)(b * Hh) + x) * Nn + 8 * g;
    const short* X1 = X0 + (size_t)16 * Nn;

    f32x4 acc0 = {0.f, 0.f, 0.f, 0.f};
    f32x4 acc1 = {0.f, 0.f, 0.f, 0.f};
    int ks0 = w * (KSTEPS / 4);
#pragma unroll 4
    for (int ks = ks0; ks < ks0 + KSTEPS / 4; ++ks) {
        bf16x8 af = *reinterpret_cast<const bf16x8*>(Arow + ks * 32);
        bf16x8 b0 = *reinterpret_cast<const bf16x8*>(X0 + ks * 32);
        bf16x8 b1 = *reinterpret_cast<const bf16x8*>(X1 + ks * 32);
        acc0 = __builtin_amdgcn_mfma_f32_16x16x32_bf16(af, b0, acc0, 0, 0, 0);
        acc1 = __builtin_amdgcn_mfma_f32_16x16x32_bf16(af, b1, acc1, 0, 0, 0);
    }
#pragma unroll
    for (int r = 0; r < 4; ++r) { sRed[w][lane][r] = acc0[r]; sRed[w][lane][4 + r] = acc1[r]; }
    __syncthreads();

    int l = t & 63, xx = l & 15, gg = l >> 4;
#pragma unroll
    for (int q = 0; q < 2; ++q) {
        int ri = (t >> 6) * 2 + q;
        float v = sRed[0][l][ri] + sRed[1][l][ri] + sRed[2][l][ri] + sRed[3][l][ri];
        int row = 4 * gg + (ri & 3);
        int c = (ri < 4) ? xx : (16 + xx);
        int bi = b * Nn + i0 + row;
        v = dinv[bi] * v + bias[c];
        v = fmaxf(v, 0.f);
        if (has_res) v += res[(size_t)bi * Hh + c];
        out[(size_t)bi * Hh + c] = v;
    }
}

// ---------------- mu / logvar heads + diag zeros ----------------
__global__ void mulv_kernel(const float* __restrict__ h3,
                            const float* __restrict__ Wmu, const float* __restrict__ bmu,
                            const float* __restrict__ Wlv, const float* __restrict__ blv,
                            float* __restrict__ mu, float* __restrict__ lv,
                            float* __restrict__ adj) {
    int t = blockIdx.x * 256 + threadIdx.x;
    if (t >= Bb * Nn * Ll) return;
    int l = t & (Ll - 1);
    int bi = t >> 4;
    const float* h = h3 + (size_t)bi * Hh;
    float am = bmu[l], av = blv[l];
#pragma unroll
    for (int c = 0; c < Hh; ++c) {
        float hv = h[c];
        am = fmaf(hv, Wmu[c * Ll + l], am);
        av = fmaf(hv, Wlv[c * Ll + l], av);
    }
    mu[(size_t)bi * Ll + l] = am;
    lv[(size_t)bi * Ll + l] = av;
    if (l == 0) {
        int b = bi / Nn, i = bi - b * Nn;
        adj[(size_t)b * Nn * Nn + (size_t)i * Nn + i] = 0.f;
    }
}

// ---------------- U/V precompute: U = z@E1_top + e1, V = z@E1_bot ----------------
__global__ void uv_kernel(const float* __restrict__ z, const float* __restrict__ E1,
                          const float* __restrict__ e1,
                          float* __restrict__ U, float* __restrict__ V) {
    int t = blockIdx.x * 256 + threadIdx.x;
    if (t >= Bb * Nn * 64) return;
    int c = t & 63;
    int bi = t >> 6;
    const float* zr = z + (size_t)bi * Ll;
    float au = e1[c], av = 0.f;
#pragma unroll
    for (int m = 0; m < Ll; ++m) {
        float zv = zr[m];
        au = fmaf(zv, E1[m * 64 + c], au);
        av = fmaf(zv, E1[(16 + m) * 64 + c], av);
    }
    U[t] = au;
    V[t] = av;
}

// ---------------- edge MLP: one wave per 16x16 (i,j) region ----------------
__global__ __launch_bounds__(256) void edge_kernel(
    const float* __restrict__ U, const float* __restrict__ V,
    const float* __restrict__ E2, const float* __restrict__ e2,
    const float* __restrict__ E3, const float* __restrict__ e3,
    float* __restrict__ adj) {
    __shared__ float sU[4][16][68];      // 17.4 KB, U rows of the region
    __shared__ float sW[4][16][20];      // 5.1 KB, result tile (transpose / diag)
    int t = threadIdx.x, lane = t & 63, w = t >> 6;
    int x = lane & 15, g = lane >> 4;

    int region = blockIdx.x * 4 + w;
    int b = 0, tr = region;
    if (tr >= TREG) { b = 1; tr -= TREG; }
    // invert tr -> (ib, jb), jb >= ib; offset(ib) = ib*Nb - ib*(ib-1)/2
    float ft = (float)tr;
    int ib = (int)((193.0f - sqrtf(193.0f * 193.0f - 8.0f * ft)) * 0.5f);
    ib = ib < 0 ? 0 : (ib > Nb - 1 ? Nb - 1 : ib);
    while (ib < Nb - 1 && (ib + 1) * Nb - ((ib + 1) * ib) / 2 <= tr) ++ib;
    while (ib > 0 && ib * Nb - (ib * (ib - 1)) / 2 > tr) --ib;
    int off = ib * Nb - (ib * (ib - 1)) / 2;
    int jb = ib + (tr - off);
    int i0 = ib * 16, j0 = jb * 16;
    bool diag = (ib == jb);

    // B-fragments of E2 (loop-invariant)
    bf16x8 bfr[2][2];
#pragma unroll
    for (int s = 0; s < 2; ++s)
#pragma unroll
        for (int nt = 0; nt < 2; ++nt)
#pragma unroll
            for (int jj = 0; jj < 8; ++jj)
                bfr[s][nt][jj] = f2bf(E2[(32 * s + 8 * g + jj) * Hh + 16 * nt + x]);

    float e2c0 = e2[x], e2c1 = e2[16 + x];
    float E3c0 = E3[x], E3c1 = E3[16 + x];
    float e3s = e3[0];

    // V fragment (register-resident, M-tile-invariant): row j0+x, k slices at 8g
    const float* Vp = V + ((size_t)b * Nn + j0 + x) * 64 + 8 * g;
    float4 v0 = *reinterpret_cast<const float4*>(Vp);
    float4 v1 = *reinterpret_cast<const float4*>(Vp + 4);
    float4 v2 = *reinterpret_cast<const float4*>(Vp + 32);
    float4 v3 = *reinterpret_cast<const float4*>(Vp + 36);

    // stage U rows of region into LDS
    {
        int r = lane >> 2, cq = (lane & 3) * 4;
        const float* Up = U + ((size_t)b * Nn + i0 + r) * 64 + cq;
#pragma unroll
        for (int q = 0; q < 4; ++q) {
            float4 u = *reinterpret_cast<const float4*>(Up + q * 16);
            *reinterpret_cast<float4*>(&sU[w][r][cq + q * 16]) = u;
        }
    }
    if (lane < 16) sW[w][lane][lane] = 0.f;   // diag zeros (used by diag regions)

#pragma unroll 4
    for (int r = 0; r < 16; ++r) {
        float4 u0 = *reinterpret_cast<const float4*>(&sU[w][r][8 * g]);
        float4 u1 = *reinterpret_cast<const float4*>(&sU[w][r][8 * g + 4]);
        float4 u2 = *reinterpret_cast<const float4*>(&sU[w][r][32 + 8 * g]);
        float4 u3 = *reinterpret_cast<const float4*>(&sU[w][r][36 + 8 * g]);

        bf16x8 af0, af1;
        af0[0] = f2bf(fmaxf(u0.x + v0.x, 0.f));
        af0[1] = f2bf(fmaxf(u0.y + v0.y, 0.f));
        af0[2] = f2bf(fmaxf(u0.z + v0.z, 0.f));
        af0[3] = f2bf(fmaxf(u0.w + v0.w, 0.f));
        af0[4] = f2bf(fmaxf(u1.x + v1.x, 0.f));
        af0[5] = f2bf(fmaxf(u1.y + v1.y, 0.f));
        af0[6] = f2bf(fmaxf(u1.z + v1.z, 0.f));
        af0[7] = f2bf(fmaxf(u1.w + v1.w, 0.f));
        af1[0] = f2bf(fmaxf(u2.x + v2.x, 0.f));
        af1[1] = f2bf(fmaxf(u2.y + v2.y, 0.f));
        af1[2] = f2bf(fmaxf(u2.z + v2.z, 0.f));
        af1[3] = f2bf(fmaxf(u2.w + v2.w, 0.f));
        af1[4] = f2bf(fmaxf(u3.x + v3.x, 0.f));
        af1[5] = f2bf(fmaxf(u3.y + v3.y, 0.f));
        af1[6] = f2bf(fmaxf(u3.z + v3.z, 0.f));
        af1[7] = f2bf(fmaxf(u3.w + v3.w, 0.f));

        f32x4 acc0 = {0.f, 0.f, 0.f, 0.f};
        f32x4 acc1 = {0.f, 0.f, 0.f, 0.f};
        acc0 = __builtin_amdgcn_mfma_f32_16x16x32_bf16(af0, bfr[0][0], acc0, 0, 0, 0);
        acc0 = __builtin_amdgcn_mfma_f32_16x16x32_bf16(af1, bfr[1][0], acc0, 0, 0, 0);
        acc1 = __builtin_amdgcn_mfma_f32_16x16x32_bf16(af0, bfr[0][1], acc1, 0, 0, 0);
        acc1 = __builtin_amdgcn_mfma_f32_16x16x32_bf16(af1, bfr[1][1], acc1, 0, 0, 0);

        float part[4];
#pragma unroll
        for (int rg = 0; rg < 4; ++rg) {
            float h20 = fmaxf(acc0[rg] + e2c0, 0.f);
            float h21 = fmaxf(acc1[rg] + e2c1, 0.f);
            part[rg] = fmaf(h20, E3c0, h21 * E3c1);
        }
#pragma unroll
        for (int m = 1; m < 16; m <<= 1)
#pragma unroll
            for (int rg = 0; rg < 4; ++rg)
                part[rg] += __shfl_xor(part[rg], m, 64);

        if (x < 4) {
            int c = 4 * g + x;
            float logit = part[x] + e3s;
            float wv = 1.f / (1.f + __expf(-logit));
            if (!diag) {
                adj[((size_t)b * Nn + i0 + r) * Nn + j0 + c] = wv;  // direct (coalesced line)
                sW[w][c][r] = wv;                                   // for transpose store
            } else if (c > r) {
                sW[w][r][c] = wv;
                sW[w][c][r] = wv;
            }
        }
    }

    // region-level coalesced store of the second block
    {
        int rr = lane >> 2, m4 = (lane & 3) * 4;
        float4 wv4 = *reinterpret_cast<const float4*>(&sW[w][rr][m4]);
        if (!diag)
            *reinterpret_cast<float4*>(&adj[((size_t)b * Nn + j0 + rr) * Nn + i0 + m4]) = wv4;
        else
            *reinterpret_cast<float4*>(&adj[((size_t)b * Nn + i0 + rr) * Nn + i0 + m4]) = wv4;
    }
}

extern "C" void kernel_launch(void* const* d_in, const int* in_sizes, int n_in,
                              void* d_out, int out_size, void* d_ws, size_t ws_size,
                              hipStream_t stream) {
    const float* A   = (const float*)d_in[0];
    const float* emb = (const float*)d_in[1];
    const float* W1  = (const float*)d_in[2];  const float* b1  = (const float*)d_in[3];
    const float* W2  = (const float*)d_in[4];  const float* b2  = (const float*)d_in[5];
    const float* W3  = (const float*)d_in[6];  const float* b3  = (const float*)d_in[7];
    const float* Wmu = (const float*)d_in[8];  const float* bmu = (const float*)d_in[9];
    const float* Wlv = (const float*)d_in[10]; const float* blv = (const float*)d_in[11];
    const float* E1  = (const float*)d_in[12]; const float* e1  = (const float*)d_in[13];
    const float* E2  = (const float*)d_in[14]; const float* e2  = (const float*)d_in[15];
    const float* E3  = (const float*)d_in[16]; const float* e3  = (const float*)d_in[17];

    float* out = (float*)d_out;
    float* ws  = (float*)d_ws;
    // ws layout (floats): dinv[3072] hA[98304] hB[98304] U[196608] V[196608] xsT[49152 f32-equiv]
    float* dinv = ws;
    float* hA   = ws + 3072;
    float* hB   = ws + 101376;
    float* Ubuf = ws + 199680;
    float* Vbuf = ws + 396288;
    __hip_bfloat16* xsT = (__hip_bfloat16*)(ws + 592896);
    // Abf (9.4 MB) aliases the adj region of d_out: written by prep, read by props,
    // then adj is overwritten by mulv(diag)/edge afterwards — stream-ordered, safe.
    __hip_bfloat16* Abf = (__hip_bfloat16*)out;

    float* mu_out = out + (size_t)Bb * Nn * Nn;
    float* lv_out = mu_out + (size_t)Bb * Nn * Ll;

    prep_kernel<<<(Bb * Nn + 3) / 4, 256, 0, stream>>>(A, Abf, dinv);

    dim3 xg(6, Bb * Hh);
    // layer 1
    xsT_kernel<<<xg, 256, 0, stream>>>(emb, 0, 8, W1, dinv, xsT);
    prop_kernel<<<Bb * Nb, 256, 0, stream>>>(Abf, xsT, dinv, b1, nullptr, hA, 0);
    // layer 2
    xsT_kernel<<<xg, 256, 0, stream>>>(hA, Nn * Hh, Hh, W2, dinv, xsT);
    prop_kernel<<<Bb * Nb, 256, 0, stream>>>(Abf, xsT, dinv, b2, hA, hB, 1);
    // layer 3
    xsT_kernel<<<xg, 256, 0, stream>>>(hB, Nn * Hh, Hh, W3, dinv, xsT);
    prop_kernel<<<Bb * Nb, 256, 0, stream>>>(Abf, xsT, dinv, b3, hB, hA, 1);

    mulv_kernel<<<(Bb * Nn * Ll + 255) / 256, 256, 0, stream>>>(hA, Wmu, bmu, Wlv, blv,
                                                                mu_out, lv_out, out);

    uv_kernel<<<(Bb * Nn * 64 + 255) / 256, 256, 0, stream>>>(mu_out, E1, e1, Ubuf, Vbuf);

    edge_kernel<<<(2 * TREG) / 4, 256, 0, stream>>>(Ubuf, Vbuf, E2, e2, E3, e3, out);
}

// Round 5
// 68.935 us; speedup vs baseline: 5.7129x; 1.6124x over previous
//
#include <hip/hip_runtime.h>
#include <hip/hip_bf16.h>
#include <math.h>

#define Nn 1536
#define Bb 2
#define Hh 32
#define Ll 16
#define Nb 96          // Nn/16
#define TREG 4656      // Nb*(Nb+1)/2 regions per batch
#define KSTEPS 48      // 1536/32

typedef short bf16x8 __attribute__((ext_vector_type(8)));
typedef _Float16 f16x8 __attribute__((ext_vector_type(8)));
typedef float f32x4 __attribute__((ext_vector_type(4)));
typedef short short4v __attribute__((ext_vector_type(4)));

__device__ __forceinline__ short f2bf(float x) {
    __hip_bfloat16 h = __float2bfloat16(x);
    return *reinterpret_cast<short*>(&h);
}

// ---------------- prep: rowsum -> dinv, and A -> bf16 with self-loop fill on diag ----------------
__global__ void prep_kernel(const float* __restrict__ A,
                            __hip_bfloat16* __restrict__ Abf,
                            float* __restrict__ dinv) {
    int w = threadIdx.x >> 6;
    int lane = threadIdx.x & 63;
    int bi = blockIdx.x * 4 + w;
    if (bi >= Bb * Nn) return;
    int i = (bi >= Nn) ? bi - Nn : bi;
    const float* Arow = A + (size_t)bi * Nn;
    short* Brow = (short*)Abf + (size_t)bi * Nn;
    float s = 0.f;
#pragma unroll
    for (int it = 0; it < 6; ++it) {
        int j = it * 256 + lane * 4;
        float4 a4 = *reinterpret_cast<const float4*>(Arow + j);
        s += a4.x + a4.y + a4.z + a4.w;
        float e0 = (j + 0 == i) ? ((a4.x == 0.f) ? 1.f : a4.x) : a4.x;
        float e1 = (j + 1 == i) ? ((a4.y == 0.f) ? 1.f : a4.y) : a4.y;
        float e2v = (j + 2 == i) ? ((a4.z == 0.f) ? 1.f : a4.z) : a4.z;
        float e3v = (j + 3 == i) ? ((a4.w == 0.f) ? 1.f : a4.w) : a4.w;
        short4v sv = { f2bf(e0), f2bf(e1), f2bf(e2v), f2bf(e3v) };
        *reinterpret_cast<short4v*>(Brow + j) = sv;
    }
#pragma unroll
    for (int o = 32; o > 0; o >>= 1) s += __shfl_down(s, o, 64);
    if (lane == 0) {
        float d = Arow[i];
        float fill = (d == 0.f) ? 1.f : d;
        float deg = s - d + fill;
        dinv[bi] = (deg > 0.f) ? (1.f / sqrtf(deg)) : 0.f;
    }
}

// ---------------- xsT (layer 1 only): xsT[b][c][i] = bf16( dinv_i * (emb @ W1)[i][c] ) ----------------
__global__ void xsT_kernel(const float* __restrict__ x, int Cin,
                           const float* __restrict__ W,
                           const float* __restrict__ dinv,
                           __hip_bfloat16* __restrict__ xsT) {
    int bc = blockIdx.y;                 // b*32 + c
    int b = bc >> 5, c = bc & 31;
    int i = blockIdx.x * 256 + threadIdx.x;
    const float* xr = x + (size_t)i * Cin;   // emb broadcast over batch
    float acc = 0.f;
    for (int m = 0; m < Cin; ++m) acc = fmaf(xr[m], W[m * Hh + c], acc);
    acc *= dinv[b * Nn + i];
    ((short*)xsT)[(size_t)bc * Nn + i] = f2bf(acc);
}

// ---------------- GCN propagation via MFMA + fused epilogues ----------------
// out = relu(dinv_i * (Abf @ xs) + bias) [+ res]
// epilogue A (Wn != 0):   xsT_next[b][c][i] = bf16(dinv_i * (out @ Wn)[i][c])
// epilogue B (final): mu/lv heads, then U = mu@E1_top + e1, V = mu@E1_bot (fp16)
__global__ __launch_bounds__(256) void prop_kernel(
    const __hip_bfloat16* __restrict__ Abf, const __hip_bfloat16* __restrict__ xsT,
    const float* __restrict__ dinv, const float* __restrict__ bias,
    const float* __restrict__ res, float* __restrict__ out, int has_res,
    const float* __restrict__ Wn, __hip_bfloat16* __restrict__ xsT_next,
    int final_stage,
    const float* __restrict__ Wmu, const float* __restrict__ bmu,
    const float* __restrict__ Wlv, const float* __restrict__ blv,
    const float* __restrict__ E1, const float* __restrict__ e1,
    float* __restrict__ mu, float* __restrict__ lv,
    _Float16* __restrict__ Uh, _Float16* __restrict__ Vh) {
    __shared__ float sRed[4][64][8];
    __shared__ float sOut[16][33];
    __shared__ float sWn[32][32];
    __shared__ float sMu[16][16];
    int t = threadIdx.x, lane = t & 63, w = t >> 6;
    int x = lane & 15, g = lane >> 4;
    int mt = blockIdx.x;
    int b = mt / Nb, it = mt - b * Nb;
    int i0 = it * 16;

    if (Wn) {  // stage next-layer weight early (overlaps MFMA loop)
        for (int k = t; k < 1024; k += 256) sWn[k >> 5][k & 31] = Wn[k];
    }

    const short* Arow = (const short*)Abf + ((size_t)b * Nn + i0 + x) * Nn + 8 * g;
    const short* X0 = (const short*)xsT + ((size_t)(b * Hh) + x) * Nn + 8 * g;
    const short* X1 = X0 + (size_t)16 * Nn;

    f32x4 acc0 = {0.f, 0.f, 0.f, 0.f};
    f32x4 acc1 = {0.f, 0.f, 0.f, 0.f};
    int ks0 = w * (KSTEPS / 4);
#pragma unroll 4
    for (int ks = ks0; ks < ks0 + KSTEPS / 4; ++ks) {
        bf16x8 af = *reinterpret_cast<const bf16x8*>(Arow + ks * 32);
        bf16x8 b0 = *reinterpret_cast<const bf16x8*>(X0 + ks * 32);
        bf16x8 b1 = *reinterpret_cast<const bf16x8*>(X1 + ks * 32);
        acc0 = __builtin_amdgcn_mfma_f32_16x16x32_bf16(af, b0, acc0, 0, 0, 0);
        acc1 = __builtin_amdgcn_mfma_f32_16x16x32_bf16(af, b1, acc1, 0, 0, 0);
    }
#pragma unroll
    for (int r = 0; r < 4; ++r) { sRed[w][lane][r] = acc0[r]; sRed[w][lane][4 + r] = acc1[r]; }
    __syncthreads();

    int l = t & 63, xx = l & 15, gg = l >> 4;
#pragma unroll
    for (int q = 0; q < 2; ++q) {
        int ri = (t >> 6) * 2 + q;
        float v = sRed[0][l][ri] + sRed[1][l][ri] + sRed[2][l][ri] + sRed[3][l][ri];
        int row = 4 * gg + (ri & 3);
        int c = (ri < 4) ? xx : (16 + xx);
        int bi = b * Nn + i0 + row;
        v = dinv[bi] * v + bias[c];
        v = fmaxf(v, 0.f);
        if (has_res) v += res[(size_t)bi * Hh + c];
        out[(size_t)bi * Hh + c] = v;
        sOut[row][c] = v;
    }
    __syncthreads();

    if (Wn) {
        for (int k = t; k < 512; k += 256) {
            int r = k >> 5, c = k & 31;
            float acc = 0.f;
#pragma unroll
            for (int m = 0; m < 32; ++m) acc = fmaf(sOut[r][m], sWn[m][c], acc);
            int bi = b * Nn + i0 + r;
            ((short*)xsT_next)[(size_t)(b * Hh + c) * Nn + i0 + r] = f2bf(dinv[bi] * acc);
        }
    }
    if (final_stage) {
        {  // mu / logvar heads (t < 256 exactly covers 16 rows x 16 latents)
            int r = t >> 4, ll = t & 15;
            float am = bmu[ll], av = blv[ll];
#pragma unroll
            for (int m = 0; m < 32; ++m) {
                float hv = sOut[r][m];
                am = fmaf(hv, Wmu[m * Ll + ll], am);
                av = fmaf(hv, Wlv[m * Ll + ll], av);
            }
            size_t o = ((size_t)b * Nn + i0 + r) * Ll + ll;
            mu[o] = am; lv[o] = av;
            sMu[r][ll] = am;
        }
        __syncthreads();
#pragma unroll
        for (int q = 0; q < 4; ++q) {
            int idx = q * 256 + t;
            int r = idx >> 6, c = idx & 63;
            float ua = e1[c], va = 0.f;
#pragma unroll
            for (int m = 0; m < Ll; ++m) {
                float zm = sMu[r][m];
                ua = fmaf(zm, E1[m * 64 + c], ua);
                va = fmaf(zm, E1[(16 + m) * 64 + c], va);
            }
            size_t o = ((size_t)b * Nn + i0 + r) * 64 + c;
            Uh[o] = (_Float16)ua;
            Vh[o] = (_Float16)va;
        }
    }
}

// ---------------- edge MLP: one wave per 16x16 (i,j) region, fp16 h1, swapped MFMA ----------------
__global__ __launch_bounds__(256) void edge_kernel(
    const _Float16* __restrict__ Uh, const _Float16* __restrict__ Vh,
    const float* __restrict__ E2, const float* __restrict__ e2,
    const float* __restrict__ E3, const float* __restrict__ e3,
    float* __restrict__ adj) {
    __shared__ _Float16 sUp[4][16][4][16];   // 8 KB: [wave][row][g][k-halves]
    __shared__ float sW[4][16][20];          // 5.1 KB: result tile (transpose / diag)
    int t = threadIdx.x, lane = t & 63, w = t >> 6;
    int x = lane & 15, g = lane >> 4;

    int region = blockIdx.x * 4 + w;
    int b = 0, tr = region;
    if (tr >= TREG) { b = 1; tr -= TREG; }
    // invert tr -> (ib, jb), jb >= ib
    float ft = (float)tr;
    int ib = (int)((193.0f - sqrtf(193.0f * 193.0f - 8.0f * ft)) * 0.5f);
    ib = ib < 0 ? 0 : (ib > Nb - 1 ? Nb - 1 : ib);
    while (ib < Nb - 1 && (ib + 1) * Nb - ((ib + 1) * ib) / 2 <= tr) ++ib;
    while (ib > 0 && ib * Nb - (ib * (ib - 1)) / 2 > tr) --ib;
    int off = ib * Nb - (ib * (ib - 1)) / 2;
    int jb = ib + (tr - off);
    int i0 = ib * 16, j0 = jb * 16;
    bool diag = (ib == jb);

    // A-fragments of E2^T (loop-invariant): ea[ct][ks][j] = E2[32ks+8g+j][16ct + x]
    f16x8 ea[2][2];
#pragma unroll
    for (int ct = 0; ct < 2; ++ct)
#pragma unroll
        for (int ks = 0; ks < 2; ++ks)
#pragma unroll
            for (int jj = 0; jj < 8; ++jj)
                ea[ct][ks][jj] = (_Float16)E2[(32 * ks + 8 * g + jj) * Hh + 16 * ct + x];

    // per-lane bias/head constants, indexed by channel 4g+rg (tile0) / 16+4g+rg (tile1)
    float e2a[4], e2b[4], E3a[4], E3b[4];
#pragma unroll
    for (int rg = 0; rg < 4; ++rg) {
        e2a[rg] = e2[4 * g + rg];      E3a[rg] = E3[4 * g + rg];
        e2b[rg] = e2[16 + 4 * g + rg]; E3b[rg] = E3[16 + 4 * g + rg];
    }
    float e3s = e3[0];

    // V fragments (register-resident): pair col x -> V row j0+x, k slices at 8g / 32+8g
    const f16x8* Vrow = reinterpret_cast<const f16x8*>(Vh + ((size_t)b * Nn + j0 + x) * 64);
    f16x8 vf0 = Vrow[g];
    f16x8 vf1 = Vrow[4 + g];

    // stage U rows into LDS, k-swizzled: sUp[r][(g2+r)&3] = {k 8g2..+7, k 32+8g2..+7}
    {
        int r = lane >> 2, g2 = lane & 3;
        const f16x8* Urow = reinterpret_cast<const f16x8*>(Uh + ((size_t)b * Nn + i0 + r) * 64);
        int sg = (g2 + r) & 3;
        *reinterpret_cast<f16x8*>(&sUp[w][r][sg][0]) = Urow[g2];
        *reinterpret_cast<f16x8*>(&sUp[w][r][sg][8]) = Urow[4 + g2];
    }
    if (lane < 16) sW[w][lane][lane] = 0.f;   // diag zeros

    const f16x8 fz = {0, 0, 0, 0, 0, 0, 0, 0};
#pragma unroll 4
    for (int r = 0; r < 16; ++r) {
        int sg = (g + r) & 3;
        f16x8 u0 = *reinterpret_cast<const f16x8*>(&sUp[w][r][sg][0]);
        f16x8 u1 = *reinterpret_cast<const f16x8*>(&sUp[w][r][sg][8]);

        // h1 = relu(U[i0+r] + V[j0+x]) in packed fp16 (B-fragment: col = pair x)
        f16x8 af0 = __builtin_elementwise_max(u0 + vf0, fz);
        f16x8 af1 = __builtin_elementwise_max(u1 + vf1, fz);

        // h2^T = E2^T @ h1^T, bias folded into C-init; D: row=channel, col=pair
        f32x4 acc0 = {e2a[0], e2a[1], e2a[2], e2a[3]};
        f32x4 acc1 = {e2b[0], e2b[1], e2b[2], e2b[3]};
        acc0 = __builtin_amdgcn_mfma_f32_16x16x32_f16(ea[0][0], af0, acc0, 0, 0, 0);
        acc0 = __builtin_amdgcn_mfma_f32_16x16x32_f16(ea[0][1], af1, acc0, 0, 0, 0);
        acc1 = __builtin_amdgcn_mfma_f32_16x16x32_f16(ea[1][0], af0, acc1, 0, 0, 0);
        acc1 = __builtin_amdgcn_mfma_f32_16x16x32_f16(ea[1][1], af1, acc1, 0, 0, 0);

        // layer 3: lane-local 8-channel partial, then reduce over 4 lane-groups
        float part = 0.f;
#pragma unroll
        for (int rg = 0; rg < 4; ++rg) {
            part = fmaf(fmaxf(acc0[rg], 0.f), E3a[rg], part);
            part = fmaf(fmaxf(acc1[rg], 0.f), E3b[rg], part);
        }
        part += __shfl_xor(part, 16, 64);
        part += __shfl_xor(part, 32, 64);

        if (g == 0) {
            float logit = part + e3s;
            float wv = __builtin_amdgcn_rcpf(1.f + __expf(-logit));
            if (!diag) {
                adj[((size_t)b * Nn + i0 + r) * Nn + j0 + x] = wv;  // coalesced 64B row
                sW[w][x][r] = wv;                                   // for transpose store
            } else if (x > r) {
                sW[w][r][x] = wv;
                sW[w][x][r] = wv;
            }
        }
    }

    // region-level coalesced store of the mirrored tile
    {
        int rr = lane >> 2, m4 = (lane & 3) * 4;
        float4 wv4 = *reinterpret_cast<const float4*>(&sW[w][rr][m4]);
        if (!diag)
            *reinterpret_cast<float4*>(&adj[((size_t)b * Nn + j0 + rr) * Nn + i0 + m4]) = wv4;
        else
            *reinterpret_cast<float4*>(&adj[((size_t)b * Nn + i0 + rr) * Nn + i0 + m4]) = wv4;
    }
}

extern "C" void kernel_launch(void* const* d_in, const int* in_sizes, int n_in,
                              void* d_out, int out_size, void* d_ws, size_t ws_size,
                              hipStream_t stream) {
    const float* A   = (const float*)d_in[0];
    const float* emb = (const float*)d_in[1];
    const float* W1  = (const float*)d_in[2];  const float* b1  = (const float*)d_in[3];
    const float* W2  = (const float*)d_in[4];  const float* b2  = (const float*)d_in[5];
    const float* W3  = (const float*)d_in[6];  const float* b3  = (const float*)d_in[7];
    const float* Wmu = (const float*)d_in[8];  const float* bmu = (const float*)d_in[9];
    const float* Wlv = (const float*)d_in[10]; const float* blv = (const float*)d_in[11];
    const float* E1  = (const float*)d_in[12]; const float* e1  = (const float*)d_in[13];
    const float* E2  = (const float*)d_in[14]; const float* e2  = (const float*)d_in[15];
    const float* E3  = (const float*)d_in[16]; const float* e3  = (const float*)d_in[17];

    float* out = (float*)d_out;
    float* ws  = (float*)d_ws;
    // ws layout (f32 slots): dinv[3072] hA[98304] hB[98304] xsTa[49152] xsTb[49152] Uh[98304] Vh[98304]
    float* dinv = ws;
    float* hA   = ws + 3072;
    float* hB   = ws + 101376;
    __hip_bfloat16* xsTa = (__hip_bfloat16*)(ws + 199680);
    __hip_bfloat16* xsTb = (__hip_bfloat16*)(ws + 248832);
    _Float16* Uh = (_Float16*)(ws + 297984);
    _Float16* Vh = (_Float16*)(ws + 396288);
    // Abf aliases the adj region of d_out: written by prep, read by props,
    // overwritten by edge afterwards — stream-ordered, safe.
    __hip_bfloat16* Abf = (__hip_bfloat16*)out;

    float* mu_out = out + (size_t)Bb * Nn * Nn;
    float* lv_out = mu_out + (size_t)Bb * Nn * Ll;

    prep_kernel<<<(Bb * Nn + 3) / 4, 256, 0, stream>>>(A, Abf, dinv);

    dim3 xg(6, Bb * Hh);
    xsT_kernel<<<xg, 256, 0, stream>>>(emb, 8, W1, dinv, xsTa);

    prop_kernel<<<Bb * Nb, 256, 0, stream>>>(Abf, xsTa, dinv, b1, nullptr, hA, 0,
                                             W2, xsTb, 0,
                                             nullptr, nullptr, nullptr, nullptr,
                                             nullptr, nullptr, nullptr, nullptr,
                                             nullptr, nullptr);
    prop_kernel<<<Bb * Nb, 256, 0, stream>>>(Abf, xsTb, dinv, b2, hA, hB, 1,
                                             W3, xsTa, 0,
                                             nullptr, nullptr, nullptr, nullptr,
                                             nullptr, nullptr, nullptr, nullptr,
                                             nullptr, nullptr);
    prop_kernel<<<Bb * Nb, 256, 0, stream>>>(Abf, xsTa, dinv, b3, hB, hA, 1,
                                             nullptr, nullptr, 1,
                                             Wmu, bmu, Wlv, blv, E1, e1,
                                             mu_out, lv_out, Uh, Vh);

    edge_kernel<<<(2 * TREG) / 4, 256, 0, stream>>>(Uh, Vh, E2, e2, E3, e3, out);
}

// Round 6
// 66.547 us; speedup vs baseline: 5.9178x; 1.0359x over previous
//
#include <hip/hip_runtime.h>
#include <hip/hip_bf16.h>
#include <math.h>

#define Nn 1536
#define Bb 2
#define Hh 32
#define Ll 16
#define Nb 96          // Nn/16
#define TREG 4656      // Nb*(Nb+1)/2 regions per batch
#define KSTEPS 48      // 1536/32

typedef short bf16x8 __attribute__((ext_vector_type(8)));
typedef _Float16 f16x8 __attribute__((ext_vector_type(8)));
typedef float f32x4 __attribute__((ext_vector_type(4)));
typedef short short4v __attribute__((ext_vector_type(4)));

__device__ __forceinline__ short f2bf(float x) {
    __hip_bfloat16 h = __float2bfloat16(x);
    return *reinterpret_cast<short*>(&h);
}

// ---------------- prep: rowsum -> dinv, A -> bf16 with self-loop fill, fused layer-1 xsT ----------------
// one wave per (b,i) row
__global__ void prep_kernel(const float* __restrict__ A,
                            __hip_bfloat16* __restrict__ Abf,
                            float* __restrict__ dinv,
                            const float* __restrict__ emb,
                            const float* __restrict__ W1,
                            __hip_bfloat16* __restrict__ xsT) {
    int w = threadIdx.x >> 6;
    int lane = threadIdx.x & 63;
    int bi = blockIdx.x * 4 + w;
    if (bi >= Bb * Nn) return;
    int b = (bi >= Nn) ? 1 : 0;
    int i = bi - b * Nn;
    const float* Arow = A + (size_t)bi * Nn;
    short* Brow = (short*)Abf + (size_t)bi * Nn;
    float s = 0.f;
#pragma unroll
    for (int it = 0; it < 6; ++it) {
        int j = it * 256 + lane * 4;
        float4 a4 = *reinterpret_cast<const float4*>(Arow + j);
        s += a4.x + a4.y + a4.z + a4.w;
        float e0 = (j + 0 == i) ? ((a4.x == 0.f) ? 1.f : a4.x) : a4.x;
        float e1 = (j + 1 == i) ? ((a4.y == 0.f) ? 1.f : a4.y) : a4.y;
        float e2v = (j + 2 == i) ? ((a4.z == 0.f) ? 1.f : a4.z) : a4.z;
        float e3v = (j + 3 == i) ? ((a4.w == 0.f) ? 1.f : a4.w) : a4.w;
        short4v sv = { f2bf(e0), f2bf(e1), f2bf(e2v), f2bf(e3v) };
        *reinterpret_cast<short4v*>(Brow + j) = sv;
    }
#pragma unroll
    for (int o = 1; o < 64; o <<= 1) s += __shfl_xor(s, o, 64);   // all lanes hold total
    float d = Arow[i];                                            // wave-broadcast load
    float fill = (d == 0.f) ? 1.f : d;
    float deg = s - d + fill;
    float di = (deg > 0.f) ? (1.f / sqrtf(deg)) : 0.f;
    if (lane == 0) dinv[bi] = di;
    if (lane < 32) {                                              // fused layer-1 xsT
        float acc = 0.f;
#pragma unroll
        for (int m = 0; m < 8; ++m)
            acc = fmaf(emb[(size_t)i * 8 + m], W1[m * Hh + lane], acc);
        ((short*)xsT)[(size_t)(b * Hh + lane) * Nn + i] = f2bf(di * acc);
    }
}

// ---------------- GCN propagation via MFMA + fused epilogues ----------------
__global__ __launch_bounds__(256) void prop_kernel(
    const __hip_bfloat16* __restrict__ Abf, const __hip_bfloat16* __restrict__ xsT,
    const float* __restrict__ dinv, const float* __restrict__ bias,
    const float* __restrict__ res, float* __restrict__ out, int has_res,
    const float* __restrict__ Wn, __hip_bfloat16* __restrict__ xsT_next,
    int final_stage,
    const float* __restrict__ Wmu, const float* __restrict__ bmu,
    const float* __restrict__ Wlv, const float* __restrict__ blv,
    const float* __restrict__ E1, const float* __restrict__ e1,
    float* __restrict__ mu, float* __restrict__ lv,
    _Float16* __restrict__ Uh, _Float16* __restrict__ Vh) {
    __shared__ float sRed[4][64][8];
    __shared__ float sOut[16][33];
    __shared__ float sWn[32][32];
    __shared__ float sMu[16][16];
    int t = threadIdx.x, lane = t & 63, w = t >> 6;
    int x = lane & 15, g = lane >> 4;
    int mt = blockIdx.x;
    int b = mt / Nb, it = mt - b * Nb;
    int i0 = it * 16;

    if (Wn) {
        for (int k = t; k < 1024; k += 256) sWn[k >> 5][k & 31] = Wn[k];
    }

    const short* Arow = (const short*)Abf + ((size_t)b * Nn + i0 + x) * Nn + 8 * g;
    const short* X0 = (const short*)xsT + ((size_t)(b * Hh) + x) * Nn + 8 * g;
    const short* X1 = X0 + (size_t)16 * Nn;

    f32x4 acc0 = {0.f, 0.f, 0.f, 0.f};
    f32x4 acc1 = {0.f, 0.f, 0.f, 0.f};
    int ks0 = w * (KSTEPS / 4);
#pragma unroll 4
    for (int ks = ks0; ks < ks0 + KSTEPS / 4; ++ks) {
        bf16x8 af = *reinterpret_cast<const bf16x8*>(Arow + ks * 32);
        bf16x8 b0 = *reinterpret_cast<const bf16x8*>(X0 + ks * 32);
        bf16x8 b1 = *reinterpret_cast<const bf16x8*>(X1 + ks * 32);
        acc0 = __builtin_amdgcn_mfma_f32_16x16x32_bf16(af, b0, acc0, 0, 0, 0);
        acc1 = __builtin_amdgcn_mfma_f32_16x16x32_bf16(af, b1, acc1, 0, 0, 0);
    }
#pragma unroll
    for (int r = 0; r < 4; ++r) { sRed[w][lane][r] = acc0[r]; sRed[w][lane][4 + r] = acc1[r]; }
    __syncthreads();

    int l = t & 63, xx = l & 15, gg = l >> 4;
#pragma unroll
    for (int q = 0; q < 2; ++q) {
        int ri = (t >> 6) * 2 + q;
        float v = sRed[0][l][ri] + sRed[1][l][ri] + sRed[2][l][ri] + sRed[3][l][ri];
        int row = 4 * gg + (ri & 3);
        int c = (ri < 4) ? xx : (16 + xx);
        int bi = b * Nn + i0 + row;
        v = dinv[bi] * v + bias[c];
        v = fmaxf(v, 0.f);
        if (has_res) v += res[(size_t)bi * Hh + c];
        out[(size_t)bi * Hh + c] = v;
        sOut[row][c] = v;
    }
    __syncthreads();

    if (Wn) {
        for (int k = t; k < 512; k += 256) {
            int r = k >> 5, c = k & 31;
            float acc = 0.f;
#pragma unroll
            for (int m = 0; m < 32; ++m) acc = fmaf(sOut[r][m], sWn[m][c], acc);
            int bi = b * Nn + i0 + r;
            ((short*)xsT_next)[(size_t)(b * Hh + c) * Nn + i0 + r] = f2bf(dinv[bi] * acc);
        }
    }
    if (final_stage) {
        {
            int r = t >> 4, ll = t & 15;
            float am = bmu[ll], av = blv[ll];
#pragma unroll
            for (int m = 0; m < 32; ++m) {
                float hv = sOut[r][m];
                am = fmaf(hv, Wmu[m * Ll + ll], am);
                av = fmaf(hv, Wlv[m * Ll + ll], av);
            }
            size_t o = ((size_t)b * Nn + i0 + r) * Ll + ll;
            mu[o] = am; lv[o] = av;
            sMu[r][ll] = am;
        }
        __syncthreads();
#pragma unroll
        for (int q = 0; q < 4; ++q) {
            int idx = q * 256 + t;
            int r = idx >> 6, c = idx & 63;
            float ua = e1[c], va = 0.f;
#pragma unroll
            for (int m = 0; m < Ll; ++m) {
                float zm = sMu[r][m];
                ua = fmaf(zm, E1[m * 64 + c], ua);
                va = fmaf(zm, E1[(16 + m) * 64 + c], va);
            }
            size_t o = ((size_t)b * Nn + i0 + r) * 64 + c;
            Uh[o] = (_Float16)ua;
            Vh[o] = (_Float16)va;
        }
    }
}

// ---------------- edge MLP: one wave per TWO 16x16 (i,j) regions ----------------
__global__ __launch_bounds__(256) void edge_kernel(
    const _Float16* __restrict__ Uh, const _Float16* __restrict__ Vh,
    const float* __restrict__ E2, const float* __restrict__ e2,
    const float* __restrict__ E3, const float* __restrict__ e3,
    float* __restrict__ adj) {
    __shared__ _Float16 sUp[4][16][4][16];   // 8 KB: [wave][row][k-group][k-halves]
    __shared__ float sW[4][16][20];          // 5.1 KB: result tile (transpose / diag)
    int t = threadIdx.x, lane = t & 63, w = t >> 6;
    int x = lane & 15, g = lane >> 4;

    // ---- per-wave invariants (amortized over 2 regions) ----
    // A-fragments of E2^T: ea[ct][ks][j] = E2[32ks+8g+j][16ct + x]
    f16x8 ea[2][2];
#pragma unroll
    for (int ct = 0; ct < 2; ++ct)
#pragma unroll
        for (int ks = 0; ks < 2; ++ks)
#pragma unroll
            for (int jj = 0; jj < 8; ++jj)
                ea[ct][ks][jj] = (_Float16)E2[(32 * ks + 8 * g + jj) * Hh + 16 * ct + x];

    float e2a[4], e2b[4], E3a[4], E3b[4];
#pragma unroll
    for (int rg = 0; rg < 4; ++rg) {
        e2a[rg] = e2[4 * g + rg];      E3a[rg] = E3[4 * g + rg];
        e2b[rg] = e2[16 + 4 * g + rg]; E3b[rg] = E3[16 + 4 * g + rg];
    }
    float e3s = e3[0];

    // ---- first region index for this wave ----
    int wid = blockIdx.x * 4 + w;
    int tr = wid * 2;
    int b = 0;
    if (tr >= TREG) { b = 1; tr -= TREG; }
    float ft = (float)tr;
    int ib = (int)((193.0f - sqrtf(193.0f * 193.0f - 8.0f * ft)) * 0.5f);
    ib = ib < 0 ? 0 : (ib > Nb - 1 ? Nb - 1 : ib);
    while (ib < Nb - 1 && (ib + 1) * Nb - ((ib + 1) * ib) / 2 <= tr) ++ib;
    while (ib > 0 && ib * Nb - (ib * (ib - 1)) / 2 > tr) --ib;
    int jb = ib + (tr - (ib * Nb - (ib * (ib - 1)) / 2));

    const f16x8 fz = {0, 0, 0, 0, 0, 0, 0, 0};

#pragma unroll 1
    for (int itr = 0; itr < 2; ++itr) {
        int i0 = ib * 16, j0 = jb * 16;
        bool diag = (ib == jb);

        // V fragments (register-resident): pair col x -> V row j0+x
        const f16x8* Vrow = reinterpret_cast<const f16x8*>(Vh + ((size_t)b * Nn + j0 + x) * 64);
        f16x8 vf0 = Vrow[g];
        f16x8 vf1 = Vrow[4 + g];

        // stage U rows into LDS, k-swizzled to spread write banks
        {
            int r = lane >> 2, g2 = lane & 3;
            const f16x8* Urow = reinterpret_cast<const f16x8*>(Uh + ((size_t)b * Nn + i0 + r) * 64);
            int sg = (g2 + r) & 3;
            *reinterpret_cast<f16x8*>(&sUp[w][r][sg][0]) = Urow[g2];
            *reinterpret_cast<f16x8*>(&sUp[w][r][sg][8]) = Urow[4 + g2];
        }
        if (lane < 16) sW[w][lane][lane] = 0.f;   // diag zeros

#pragma unroll 4
        for (int r = 0; r < 16; ++r) {
            int sg = (g + r) & 3;
            f16x8 u0 = *reinterpret_cast<const f16x8*>(&sUp[w][r][sg][0]);
            f16x8 u1 = *reinterpret_cast<const f16x8*>(&sUp[w][r][sg][8]);

            // h1 = relu(U[i0+r] + V[j0+x]) packed fp16 (B-fragment: col = pair x)
            f16x8 af0 = __builtin_elementwise_max(u0 + vf0, fz);
            f16x8 af1 = __builtin_elementwise_max(u1 + vf1, fz);

            // h2^T = E2^T @ h1^T, bias folded into C-init; D: row=channel, col=pair
            f32x4 acc0 = {e2a[0], e2a[1], e2a[2], e2a[3]};
            f32x4 acc1 = {e2b[0], e2b[1], e2b[2], e2b[3]};
            acc0 = __builtin_amdgcn_mfma_f32_16x16x32_f16(ea[0][0], af0, acc0, 0, 0, 0);
            acc0 = __builtin_amdgcn_mfma_f32_16x16x32_f16(ea[0][1], af1, acc0, 0, 0, 0);
            acc1 = __builtin_amdgcn_mfma_f32_16x16x32_f16(ea[1][0], af0, acc1, 0, 0, 0);
            acc1 = __builtin_amdgcn_mfma_f32_16x16x32_f16(ea[1][1], af1, acc1, 0, 0, 0);

            // layer 3: lane-local 8-channel partial, reduce over 4 lane-groups
            float part = 0.f;
#pragma unroll
            for (int rg = 0; rg < 4; ++rg) {
                part = fmaf(fmaxf(acc0[rg], 0.f), E3a[rg], part);
                part = fmaf(fmaxf(acc1[rg], 0.f), E3b[rg], part);
            }
            part += __shfl_xor(part, 16, 64);
            part += __shfl_xor(part, 32, 64);

            if (g == 0) {
                float logit = part + e3s;
                float wv = __builtin_amdgcn_rcpf(1.f + __expf(-logit));
                if (!diag) {
                    adj[((size_t)b * Nn + i0 + r) * Nn + j0 + x] = wv;  // coalesced row
                    sW[w][x][r] = wv;                                   // transpose store
                } else if (x > r) {
                    sW[w][r][x] = wv;
                    sW[w][x][r] = wv;
                }
            }
        }

        // region-level coalesced store of the mirrored tile
        {
            int rr = lane >> 2, m4 = (lane & 3) * 4;
            float4 wv4 = *reinterpret_cast<const float4*>(&sW[w][rr][m4]);
            if (!diag)
                *reinterpret_cast<float4*>(&adj[((size_t)b * Nn + j0 + rr) * Nn + i0 + m4]) = wv4;
            else
                *reinterpret_cast<float4*>(&adj[((size_t)b * Nn + i0 + rr) * Nn + i0 + m4]) = wv4;
        }

        // advance to next region (triangular row-major)
        if (++jb == Nb) {
            ++ib; jb = ib;
            if (ib == Nb) { b = 1; ib = 0; jb = 0; }
        }
    }
}

extern "C" void kernel_launch(void* const* d_in, const int* in_sizes, int n_in,
                              void* d_out, int out_size, void* d_ws, size_t ws_size,
                              hipStream_t stream) {
    const float* A   = (const float*)d_in[0];
    const float* emb = (const float*)d_in[1];
    const float* W1  = (const float*)d_in[2];  const float* b1  = (const float*)d_in[3];
    const float* W2  = (const float*)d_in[4];  const float* b2  = (const float*)d_in[5];
    const float* W3  = (const float*)d_in[6];  const float* b3  = (const float*)d_in[7];
    const float* Wmu = (const float*)d_in[8];  const float* bmu = (const float*)d_in[9];
    const float* Wlv = (const float*)d_in[10]; const float* blv = (const float*)d_in[11];
    const float* E1  = (const float*)d_in[12]; const float* e1  = (const float*)d_in[13];
    const float* E2  = (const float*)d_in[14]; const float* e2  = (const float*)d_in[15];
    const float* E3  = (const float*)d_in[16]; const float* e3  = (const float*)d_in[17];

    float* out = (float*)d_out;
    float* ws  = (float*)d_ws;
    // ws layout (f32 slots): dinv[3072] hA[98304] hB[98304] xsTa[49152] xsTb[49152] Uh[98304] Vh[98304]
    float* dinv = ws;
    float* hA   = ws + 3072;
    float* hB   = ws + 101376;
    __hip_bfloat16* xsTa = (__hip_bfloat16*)(ws + 199680);
    __hip_bfloat16* xsTb = (__hip_bfloat16*)(ws + 248832);
    _Float16* Uh = (_Float16*)(ws + 297984);
    _Float16* Vh = (_Float16*)(ws + 396288);
    // Abf aliases the adj region of d_out: written by prep, read by props,
    // overwritten by edge afterwards — stream-ordered, safe.
    __hip_bfloat16* Abf = (__hip_bfloat16*)out;

    float* mu_out = out + (size_t)Bb * Nn * Nn;
    float* lv_out = mu_out + (size_t)Bb * Nn * Ll;

    prep_kernel<<<(Bb * Nn + 3) / 4, 256, 0, stream>>>(A, Abf, dinv, emb, W1, xsTa);

    prop_kernel<<<Bb * Nb, 256, 0, stream>>>(Abf, xsTa, dinv, b1, nullptr, hA, 0,
                                             W2, xsTb, 0,
                                             nullptr, nullptr, nullptr, nullptr,
                                             nullptr, nullptr, nullptr, nullptr,
                                             nullptr, nullptr);
    prop_kernel<<<Bb * Nb, 256, 0, stream>>>(Abf, xsTb, dinv, b2, hA, hB, 1,
                                             W3, xsTa, 0,
                                             nullptr, nullptr, nullptr, nullptr,
                                             nullptr, nullptr, nullptr, nullptr,
                                             nullptr, nullptr);
    prop_kernel<<<Bb * Nb, 256, 0, stream>>>(Abf, xsTa, dinv, b3, hB, hA, 1,
                                             nullptr, nullptr, 1,
                                             Wmu, bmu, Wlv, blv, E1, e1,
                                             mu_out, lv_out, Uh, Vh);

    edge_kernel<<<(2 * TREG) / (4 * 2), 256, 0, stream>>>(Uh, Vh, E2, e2, E3, e3, out);
}